// Round 7
// baseline (3552.971 us; speedup 1.0000x reference)
//
#include <hip/hip_runtime.h>
#include <hip/hip_bf16.h>
#include <cstdint>

#define IN_C 256

typedef __attribute__((ext_vector_type(8))) short bf16x8;
typedef __attribute__((ext_vector_type(8))) short s16x8;
typedef __attribute__((ext_vector_type(4))) short s16x4;
typedef __attribute__((ext_vector_type(4))) float f32x4;

// ---- bf16 helpers (RNE) ----
__device__ inline unsigned short f2bf(float f) {
    union { float f; unsigned int u; } v; v.f = f;
    unsigned int r = (v.u + 0x7fffu + ((v.u >> 16) & 1u)) >> 16;
    return (unsigned short)r;
}
__device__ inline float bf2f(unsigned short b) {
    union { unsigned int u; float f; } v; v.u = ((unsigned int)b) << 16;
    return v.f;
}
// returns .x = hi bf16 bits, .y = lo bf16 bits
__device__ inline short2 split1(float f) {
    unsigned short hb = f2bf(f);
    unsigned short lb = f2bf(f - bf2f(hb));
    return make_short2((short)hb, (short)lb);
}

// ---------------- init: deg=1 (self loop weight), cnt=0 ----------------
__global__ void init_kernel(float* __restrict__ deg, int* __restrict__ cnt, int N) {
    int i = blockIdx.x * blockDim.x + threadIdx.x;
    if (i < N) { deg[i] = 1.0f; cnt[i] = 0; }
    __threadfence();   // release to device scope for next kernel (graph-replay safety)
}

// ---------------- per-edge: degree accumulate + dst histogram ----------------
__global__ void deg_count_kernel(const int* __restrict__ ei, const float* __restrict__ w,
                                 float* __restrict__ deg, int* __restrict__ cnt, int E) {
    int e = blockIdx.x * blockDim.x + threadIdx.x;
    if (e < E) {
        int dst = ei[E + e];
        atomicAdd(&deg[dst], w[e]);
        atomicAdd(&cnt[dst], 1);
    }
    __threadfence();
}

__global__ void dinv_kernel(const float* __restrict__ deg, float* __restrict__ dinv, int N) {
    int i = blockIdx.x * blockDim.x + threadIdx.x;
    if (i < N) dinv[i] = rsqrtf(deg[i]);   // deg >= 1 always (self loop)
    __threadfence();
}

// ---------------- exclusive scan of cnt -> row_ptr (3-kernel) ----------------
#define SCAN_B 256
__global__ void scan1_kernel(const int* __restrict__ cnt, int* __restrict__ rp,
                             int* __restrict__ bsum, int N) {
    __shared__ int s[SCAN_B];
    int tid = threadIdx.x;
    int i = blockIdx.x * SCAN_B + tid;
    int v = (i < N) ? cnt[i] : 0;
    s[tid] = v;
    __syncthreads();
    for (int off = 1; off < SCAN_B; off <<= 1) {
        int t = (tid >= off) ? s[tid - off] : 0;
        __syncthreads();
        s[tid] += t;
        __syncthreads();
    }
    if (i < N) rp[i] = s[tid] - v;            // exclusive within block
    if (tid == SCAN_B - 1) bsum[blockIdx.x] = s[tid];
    __threadfence();
}

__global__ void scan2_kernel(int* __restrict__ bsum, int* __restrict__ boff, int nb) {
    __shared__ int s[SCAN_B];
    int tid = threadIdx.x;
    int v = (tid < nb) ? bsum[tid] : 0;
    s[tid] = v;
    __syncthreads();
    for (int off = 1; off < SCAN_B; off <<= 1) {
        int t = (tid >= off) ? s[tid - off] : 0;
        __syncthreads();
        s[tid] += t;
        __syncthreads();
    }
    if (tid < nb) boff[tid] = s[tid] - v;     // exclusive across blocks
    __threadfence();
}

__global__ void scan3_kernel(int* __restrict__ rp, int* __restrict__ cursor,
                             const int* __restrict__ boff, int N, int E) {
    int i = blockIdx.x * blockDim.x + threadIdx.x;
    if (i < N) {
        int r = rp[i] + boff[i >> 8];
        rp[i] = r;
        cursor[i] = r;
    }
    if (i == 0) rp[N] = E;
    __threadfence();
}

// ---------------- CSR fill with per-edge norm ----------------
__global__ void fill_kernel(const int* __restrict__ ei, const float* __restrict__ w,
                            const float* __restrict__ dinv, int* __restrict__ cursor,
                            int* __restrict__ col, float* __restrict__ val, int E) {
    int e = blockIdx.x * blockDim.x + threadIdx.x;
    if (e < E) {
        int src = ei[e];
        int dst = ei[E + e];
        int pos = atomicAdd(&cursor[dst], 1);
        // defensive clamp: never allow a wild store outside [0,E) (protects d_in)
        if (pos >= 0 && pos < E) {
            col[pos] = src;
            val[pos] = dinv[src] * w[e] * dinv[dst];
        }
    }
    __threadfence();
}

// ---------------- W prep: transpose + bf16 hi/lo split ----------------
__global__ void prep_w_kernel(const float* __restrict__ W,
                              unsigned short* __restrict__ wt_hi,
                              unsigned short* __restrict__ wt_lo) {
    int n = blockIdx.x;    // 0..255 col of W
    int k = threadIdx.x;   // 0..255 row of W
    float v = W[(size_t)k * 256 + n];
    short2 s = split1(v);
    wt_hi[(size_t)n * 256 + k] = (unsigned short)s.x;
    wt_lo[(size_t)n * 256 + k] = (unsigned short)s.y;
    __threadfence();
}

// ---------------- split-bf16 MFMA GEMM ----------------
// C16[N][256] (bf16) = A[N][256] @ B[256][256] in ~fp32 precision via 3x bf16 MFMA.
// Block: 256 thr = 4 waves; tile 128 rows x 64 cols; BK=64, single-buffered LDS.
// AFP32: A is fp32, split on the fly. else: A pre-split hi/lo bf16 arrays.
template<bool AFP32>
__global__ __launch_bounds__(256) void gemm_split_kernel(
    const float* __restrict__ Af,
    const unsigned short* __restrict__ Ahg,
    const unsigned short* __restrict__ Alg,
    const unsigned short* __restrict__ Bth,   // Wt_hi [n][k]
    const unsigned short* __restrict__ Btl,   // Wt_lo [n][k]
    unsigned short* __restrict__ C16, int Nrows)
{
    __shared__ __align__(16) short Ah[128 * 64];
    __shared__ __align__(16) short Al[128 * 64];
    __shared__ __align__(16) short Bh[64 * 64];
    __shared__ __align__(16) short Bl[64 * 64];

    const int t    = threadIdx.x;
    const int lane = t & 63;
    const int w    = t >> 6;
    const int r0   = blockIdx.x * 128;
    const int cb0  = blockIdx.y * 64;
    const int fr   = lane & 15;          // frag row (A: m-row / B: n-col)
    const int fk   = (lane >> 4) * 8;    // frag k offset
    const int wm   = w * 32;             // wave's m-band

    f32x4 acc[2][4] = {};

    for (int k0 = 0; k0 < 256; k0 += 64) {
        __syncthreads();
        // ---- stage B tile [64 n][64 k] (hi+lo) ----
#pragma unroll
        for (int c = 0; c < 2; ++c) {
            int i = c * 256 + t;
            int row = i >> 3, seg = i & 7;
            size_t g = (size_t)(cb0 + row) * 256 + k0 + seg * 8;
            *(s16x8*)&Bh[row * 64 + seg * 8] = *(const s16x8*)(Bth + g);
            *(s16x8*)&Bl[row * 64 + seg * 8] = *(const s16x8*)(Btl + g);
        }
        // ---- stage A tile [128 m][64 k] (hi+lo) ----
        if constexpr (AFP32) {
#pragma unroll
            for (int c = 0; c < 8; ++c) {
                int i = c * 256 + t;
                int row = i >> 4, seg = i & 15;
                int gr = r0 + row; if (gr > Nrows - 1) gr = Nrows - 1;
                float4 v = *(const float4*)(Af + (size_t)gr * 256 + k0 + seg * 4);
                short2 sx = split1(v.x);
                short2 sy = split1(v.y);
                short2 sz = split1(v.z);
                short2 sw = split1(v.w);
                s16x4 hv, lv;
                hv.x = sx.x; hv.y = sy.x; hv.z = sz.x; hv.w = sw.x;
                lv.x = sx.y; lv.y = sy.y; lv.z = sz.y; lv.w = sw.y;
                *(s16x4*)&Ah[row * 64 + seg * 4] = hv;
                *(s16x4*)&Al[row * 64 + seg * 4] = lv;
            }
        } else {
#pragma unroll
            for (int c = 0; c < 4; ++c) {
                int i = c * 256 + t;
                int row = i >> 3, seg = i & 7;
                int gr = r0 + row; if (gr > Nrows - 1) gr = Nrows - 1;
                size_t g = (size_t)gr * 256 + k0 + seg * 8;
                *(s16x8*)&Ah[row * 64 + seg * 8] = *(const s16x8*)(Ahg + g);
                *(s16x8*)&Al[row * 64 + seg * 8] = *(const s16x8*)(Alg + g);
            }
        }
        __syncthreads();
        // ---- compute: 2 k-steps of 32, 2m x 4n frags, 3 MFMA each ----
#pragma unroll
        for (int ks = 0; ks < 2; ++ks) {
            int ko = ks * 32 + fk;
            bf16x8 ah[2], al[2], bh[4], bl[4];
#pragma unroll
            for (int mi = 0; mi < 2; ++mi) {
                ah[mi] = *(const bf16x8*)&Ah[(wm + mi * 16 + fr) * 64 + ko];
                al[mi] = *(const bf16x8*)&Al[(wm + mi * 16 + fr) * 64 + ko];
            }
#pragma unroll
            for (int n = 0; n < 4; ++n) {
                bh[n] = *(const bf16x8*)&Bh[(n * 16 + fr) * 64 + ko];
                bl[n] = *(const bf16x8*)&Bl[(n * 16 + fr) * 64 + ko];
            }
#pragma unroll
            for (int mi = 0; mi < 2; ++mi) {
#pragma unroll
                for (int n = 0; n < 4; ++n) {
                    acc[mi][n] = __builtin_amdgcn_mfma_f32_16x16x32_bf16(ah[mi], bh[n], acc[mi][n], 0, 0, 0);
                    acc[mi][n] = __builtin_amdgcn_mfma_f32_16x16x32_bf16(ah[mi], bl[n], acc[mi][n], 0, 0, 0);
                    acc[mi][n] = __builtin_amdgcn_mfma_f32_16x16x32_bf16(al[mi], bh[n], acc[mi][n], 0, 0, 0);
                }
            }
        }
    }
    // ---- epilogue: C/D layout col=lane&15, row=(lane>>4)*4+reg; store bf16 ----
    const int rb = (lane >> 4) * 4;
#pragma unroll
    for (int mi = 0; mi < 2; ++mi) {
#pragma unroll
        for (int n = 0; n < 4; ++n) {
            int col = cb0 + n * 16 + fr;
#pragma unroll
            for (int r = 0; r < 4; ++r) {
                int row = r0 + wm + mi * 16 + rb + r;
                if (row < Nrows) C16[(size_t)row * 256 + col] = f2bf(acc[mi][n][r]);
            }
        }
    }
    __threadfence();   // make C16 visible device-wide before next kernel
}

// ---------------- CSR aggregation + self loop + bias (+relu) ----------------
// one WAVE per dst node; lane l owns channels [4l,4l+4); unroll-by-8 edge loop
// so 8 independent 512B row-gathers are in flight per wave (R4 structure:
// early-return control flow — the R6 if-wrap collapsed VGPRs to 32 and
// serialized the gather loads, 6.7x slowdown).
// Gathers bf16 rows (8B/lane), accumulates fp32.
// MODE 0: relu + write bf16 hi/lo split (feeds next MFMA GEMM)
// MODE 1: relu + fused regression head (dot with Wf, wave-reduce, 1 float/node)
template<int MODE>
__global__ __launch_bounds__(256) void agg_kernel(const unsigned short* __restrict__ h16,
                                                  const int* __restrict__ rp,
                                                  const int* __restrict__ col,
                                                  const float* __restrict__ val,
                                                  const float* __restrict__ dinv,
                                                  const float* __restrict__ bias,
                                                  unsigned short* __restrict__ out_hi,
                                                  unsigned short* __restrict__ out_lo,
                                                  const float* __restrict__ Wf,
                                                  const float* __restrict__ bf,
                                                  float* __restrict__ out,
                                                  int N) {
    int d    = blockIdx.x * 4 + (threadIdx.x >> 6);
    int lane = threadIdx.x & 63;
    if (d >= N) return;
    const ushort4* __restrict__ h4 = (const ushort4*)h16;   // row stride = 64 ushort4

    float di = dinv[d];
    ushort4 hv = h4[(size_t)d * 64 + lane];
    float self = di * di;                                // self loop, weight 1
    float4 acc;
    acc.x = self * bf2f(hv.x); acc.y = self * bf2f(hv.y);
    acc.z = self * bf2f(hv.z); acc.w = self * bf2f(hv.w);

    int s = rp[d], e = rp[d + 1];
    int j = s;
    for (; j + 8 <= e; j += 8) {
        int   c0 = col[j],     c1 = col[j + 1], c2 = col[j + 2], c3 = col[j + 3];
        int   c4 = col[j + 4], c5 = col[j + 5], c6 = col[j + 6], c7 = col[j + 7];
        float v0 = val[j],     v1 = val[j + 1], v2 = val[j + 2], v3 = val[j + 3];
        float v4 = val[j + 4], v5 = val[j + 5], v6 = val[j + 6], v7 = val[j + 7];
        ushort4 a0 = h4[(size_t)c0 * 64 + lane];
        ushort4 a1 = h4[(size_t)c1 * 64 + lane];
        ushort4 a2 = h4[(size_t)c2 * 64 + lane];
        ushort4 a3 = h4[(size_t)c3 * 64 + lane];
        ushort4 a4 = h4[(size_t)c4 * 64 + lane];
        ushort4 a5 = h4[(size_t)c5 * 64 + lane];
        ushort4 a6 = h4[(size_t)c6 * 64 + lane];
        ushort4 a7 = h4[(size_t)c7 * 64 + lane];
        acc.x = fmaf(v0, bf2f(a0.x), acc.x); acc.y = fmaf(v0, bf2f(a0.y), acc.y);
        acc.z = fmaf(v0, bf2f(a0.z), acc.z); acc.w = fmaf(v0, bf2f(a0.w), acc.w);
        acc.x = fmaf(v1, bf2f(a1.x), acc.x); acc.y = fmaf(v1, bf2f(a1.y), acc.y);
        acc.z = fmaf(v1, bf2f(a1.z), acc.z); acc.w = fmaf(v1, bf2f(a1.w), acc.w);
        acc.x = fmaf(v2, bf2f(a2.x), acc.x); acc.y = fmaf(v2, bf2f(a2.y), acc.y);
        acc.z = fmaf(v2, bf2f(a2.z), acc.z); acc.w = fmaf(v2, bf2f(a2.w), acc.w);
        acc.x = fmaf(v3, bf2f(a3.x), acc.x); acc.y = fmaf(v3, bf2f(a3.y), acc.y);
        acc.z = fmaf(v3, bf2f(a3.z), acc.z); acc.w = fmaf(v3, bf2f(a3.w), acc.w);
        acc.x = fmaf(v4, bf2f(a4.x), acc.x); acc.y = fmaf(v4, bf2f(a4.y), acc.y);
        acc.z = fmaf(v4, bf2f(a4.z), acc.z); acc.w = fmaf(v4, bf2f(a4.w), acc.w);
        acc.x = fmaf(v5, bf2f(a5.x), acc.x); acc.y = fmaf(v5, bf2f(a5.y), acc.y);
        acc.z = fmaf(v5, bf2f(a5.z), acc.z); acc.w = fmaf(v5, bf2f(a5.w), acc.w);
        acc.x = fmaf(v6, bf2f(a6.x), acc.x); acc.y = fmaf(v6, bf2f(a6.y), acc.y);
        acc.z = fmaf(v6, bf2f(a6.z), acc.z); acc.w = fmaf(v6, bf2f(a6.w), acc.w);
        acc.x = fmaf(v7, bf2f(a7.x), acc.x); acc.y = fmaf(v7, bf2f(a7.y), acc.y);
        acc.z = fmaf(v7, bf2f(a7.z), acc.z); acc.w = fmaf(v7, bf2f(a7.w), acc.w);
    }
    for (; j < e; ++j) {
        int   c = col[j];
        float v = val[j];
        ushort4 a = h4[(size_t)c * 64 + lane];
        acc.x = fmaf(v, bf2f(a.x), acc.x); acc.y = fmaf(v, bf2f(a.y), acc.y);
        acc.z = fmaf(v, bf2f(a.z), acc.z); acc.w = fmaf(v, bf2f(a.w), acc.w);
    }

    float4 b = *(const float4*)(bias + lane * 4);
    acc.x = fmaxf(acc.x + b.x, 0.0f);
    acc.y = fmaxf(acc.y + b.y, 0.0f);
    acc.z = fmaxf(acc.z + b.z, 0.0f);
    acc.w = fmaxf(acc.w + b.w, 0.0f);

    if constexpr (MODE == 0) {
        short2 sx = split1(acc.x);
        short2 sy = split1(acc.y);
        short2 sz = split1(acc.z);
        short2 sw = split1(acc.w);
        s16x4 hvv, lvv;
        hvv.x = sx.x; hvv.y = sy.x; hvv.z = sz.x; hvv.w = sw.x;
        lvv.x = sx.y; lvv.y = sy.y; lvv.z = sz.y; lvv.w = sw.y;
        *(s16x4*)(out_hi + (size_t)d * 256 + lane * 4) = hvv;
        *(s16x4*)(out_lo + (size_t)d * 256 + lane * 4) = lvv;
        __threadfence();   // a_hi/a_lo feed GEMM2 (release before kernel end)
    } else {
        float4 wf = *(const float4*)(Wf + lane * 4);
        float sdot = acc.x * wf.x + acc.y * wf.y + acc.z * wf.z + acc.w * wf.w;
        for (int off = 32; off; off >>= 1) sdot += __shfl_down(sdot, off);
        if (lane == 0) out[d] = sdot + bf[0];
    }
}

// ---------------- host launch ----------------
extern "C" void kernel_launch(void* const* d_in, const int* in_sizes, int n_in,
                              void* d_out, int out_size, void* d_ws, size_t ws_size,
                              hipStream_t stream) {
    const float* x  = (const float*)d_in[0];
    const int*   ei = (const int*)d_in[1];
    const float* w  = (const float*)d_in[2];
    const float* W1 = (const float*)d_in[3];
    const float* b1 = (const float*)d_in[4];
    const float* W2 = (const float*)d_in[5];
    const float* b2 = (const float*)d_in[6];
    const float* Wf = (const float*)d_in[7];
    const float* bf = (const float*)d_in[8];
    float* out = (float*)d_out;

    const int N = in_sizes[0] / IN_C;
    const int E = in_sizes[2];

    // workspace layout (256B aligned)
    auto align256 = [](size_t v) { return (v + 255) & ~(size_t)255; };
    char* p = (char*)d_ws;
    float* deg    = (float*)p; p += align256((size_t)N * 4);
    float* dinv   = (float*)p; p += align256((size_t)N * 4);
    int*   cnt    = (int*)p;   p += align256((size_t)N * 4);
    int*   rp     = (int*)p;   p += align256(((size_t)N + 1) * 4);
    int*   cursor = (int*)p;   p += align256((size_t)N * 4);
    int*   bsum   = (int*)p;   p += align256(SCAN_B * 4);
    int*   boff   = (int*)p;   p += align256(SCAN_B * 4);
    int*   col    = (int*)p;   p += align256((size_t)E * 4);
    float* val    = (float*)p; p += align256((size_t)E * 4);
    unsigned short* w1t_hi = (unsigned short*)p; p += align256((size_t)256 * 256 * 2);
    unsigned short* w1t_lo = (unsigned short*)p; p += align256((size_t)256 * 256 * 2);
    unsigned short* w2t_hi = (unsigned short*)p; p += align256((size_t)256 * 256 * 2);
    unsigned short* w2t_lo = (unsigned short*)p; p += align256((size_t)256 * 256 * 2);
    unsigned short* hbuf  = (unsigned short*)p; p += align256((size_t)N * 256 * 2);  // bf16 GEMM out
    unsigned short* a_hi  = (unsigned short*)p; p += align256((size_t)N * 256 * 2);
    unsigned short* a_lo  = (unsigned short*)p; p += align256((size_t)N * 256 * 2);
    (void)ws_size; (void)n_in; (void)out_size;

    const int nb_nodes = (N + 255) / 256;
    const int nb_edges = (E + 255) / 256;
    const int nb_scan  = (N + SCAN_B - 1) / SCAN_B;

    // graph normalization + CSR build
    init_kernel<<<nb_nodes, 256, 0, stream>>>(deg, cnt, N);
    deg_count_kernel<<<nb_edges, 256, 0, stream>>>(ei, w, deg, cnt, E);
    dinv_kernel<<<nb_nodes, 256, 0, stream>>>(deg, dinv, N);
    scan1_kernel<<<nb_scan, SCAN_B, 0, stream>>>(cnt, rp, bsum, N);
    scan2_kernel<<<1, SCAN_B, 0, stream>>>(bsum, boff, nb_scan);
    scan3_kernel<<<nb_nodes, 256, 0, stream>>>(rp, cursor, boff, N, E);
    fill_kernel<<<nb_edges, 256, 0, stream>>>(ei, w, dinv, cursor, col, val, E);

    // weight prep (transpose + hi/lo split)
    prep_w_kernel<<<256, 256, 0, stream>>>(W1, w1t_hi, w1t_lo);
    prep_w_kernel<<<256, 256, 0, stream>>>(W2, w2t_hi, w2t_lo);

    dim3 ggrid((N + 127) / 128, 4);
    const int nb_agg = (N + 3) / 4;

    // layer 1: GEMM (fp32 A, on-the-fly split) -> bf16 h -> agg (writes bf16 hi/lo)
    gemm_split_kernel<true><<<ggrid, 256, 0, stream>>>(x, nullptr, nullptr,
                                                       w1t_hi, w1t_lo, hbuf, N);
    agg_kernel<0><<<nb_agg, 256, 0, stream>>>(hbuf, rp, col, val, dinv, b1,
                                              a_hi, a_lo, nullptr, nullptr, nullptr, N);
    // layer 2: GEMM (pre-split bf16 A) -> bf16 h -> agg + fused head
    gemm_split_kernel<false><<<ggrid, 256, 0, stream>>>(nullptr, a_hi, a_lo,
                                                        w2t_hi, w2t_lo, hbuf, N);
    agg_kernel<1><<<nb_agg, 256, 0, stream>>>(hbuf, rp, col, val, dinv, b2,
                                              nullptr, nullptr, Wf, bf, out, N);
}

// Round 8
// 2371.108 us; speedup vs baseline: 1.4984x; 1.4984x over previous
//
#include <hip/hip_runtime.h>
#include <hip/hip_bf16.h>
#include <cstdint>

#define IN_C 256

typedef __attribute__((ext_vector_type(8))) short bf16x8;
typedef __attribute__((ext_vector_type(8))) short s16x8;
typedef __attribute__((ext_vector_type(4))) short s16x4;
typedef __attribute__((ext_vector_type(4))) float f32x4;

// ---- bf16 split helpers (RNE) ----
__device__ inline unsigned short f2bf(float f) {
    union { float f; unsigned int u; } v; v.f = f;
    unsigned int r = (v.u + 0x7fffu + ((v.u >> 16) & 1u)) >> 16;
    return (unsigned short)r;
}
__device__ inline float bf2f(unsigned short b) {
    union { unsigned int u; float f; } v; v.u = ((unsigned int)b) << 16;
    return v.f;
}
// returns .x = hi bf16 bits, .y = lo bf16 bits
__device__ inline short2 split1(float f) {
    unsigned short hb = f2bf(f);
    unsigned short lb = f2bf(f - bf2f(hb));
    return make_short2((short)hb, (short)lb);
}

// ---------------- init: deg=1 (self loop weight), cnt=0 ----------------
__global__ void init_kernel(float* __restrict__ deg, int* __restrict__ cnt, int N) {
    int i = blockIdx.x * blockDim.x + threadIdx.x;
    if (i < N) { deg[i] = 1.0f; cnt[i] = 0; }
    __threadfence();   // release to device scope (graph-replay safety)
}

// ---------------- per-edge: degree accumulate + dst histogram ----------------
__global__ void deg_count_kernel(const int* __restrict__ ei, const float* __restrict__ w,
                                 float* __restrict__ deg, int* __restrict__ cnt, int E) {
    int e = blockIdx.x * blockDim.x + threadIdx.x;
    if (e < E) {
        int dst = ei[E + e];
        atomicAdd(&deg[dst], w[e]);
        atomicAdd(&cnt[dst], 1);
    }
    __threadfence();
}

__global__ void dinv_kernel(const float* __restrict__ deg, float* __restrict__ dinv, int N) {
    int i = blockIdx.x * blockDim.x + threadIdx.x;
    if (i < N) dinv[i] = rsqrtf(deg[i]);   // deg >= 1 always (self loop)
    __threadfence();
}

// ---------------- exclusive scan of cnt -> row_ptr (3-kernel) ----------------
#define SCAN_B 256
__global__ void scan1_kernel(const int* __restrict__ cnt, int* __restrict__ rp,
                             int* __restrict__ bsum, int N) {
    __shared__ int s[SCAN_B];
    int tid = threadIdx.x;
    int i = blockIdx.x * SCAN_B + tid;
    int v = (i < N) ? cnt[i] : 0;
    s[tid] = v;
    __syncthreads();
    for (int off = 1; off < SCAN_B; off <<= 1) {
        int t = (tid >= off) ? s[tid - off] : 0;
        __syncthreads();
        s[tid] += t;
        __syncthreads();
    }
    if (i < N) rp[i] = s[tid] - v;            // exclusive within block
    if (tid == SCAN_B - 1) bsum[blockIdx.x] = s[tid];
    __threadfence();
}

__global__ void scan2_kernel(int* __restrict__ bsum, int* __restrict__ boff, int nb) {
    __shared__ int s[SCAN_B];
    int tid = threadIdx.x;
    int v = (tid < nb) ? bsum[tid] : 0;
    s[tid] = v;
    __syncthreads();
    for (int off = 1; off < SCAN_B; off <<= 1) {
        int t = (tid >= off) ? s[tid - off] : 0;
        __syncthreads();
        s[tid] += t;
        __syncthreads();
    }
    if (tid < nb) boff[tid] = s[tid] - v;     // exclusive across blocks
    __threadfence();
}

__global__ void scan3_kernel(int* __restrict__ rp, int* __restrict__ cursor,
                             const int* __restrict__ boff, int N, int E) {
    int i = blockIdx.x * blockDim.x + threadIdx.x;
    if (i < N) {
        int r = rp[i] + boff[i >> 8];
        rp[i] = r;
        cursor[i] = r;
    }
    if (i == 0) rp[N] = E;
    __threadfence();
}

// ---------------- CSR fill with per-edge norm ----------------
__global__ void fill_kernel(const int* __restrict__ ei, const float* __restrict__ w,
                            const float* __restrict__ dinv, int* __restrict__ cursor,
                            int* __restrict__ col, float* __restrict__ val, int E) {
    int e = blockIdx.x * blockDim.x + threadIdx.x;
    if (e < E) {
        int src = ei[e];
        int dst = ei[E + e];
        int pos = atomicAdd(&cursor[dst], 1);
        // defensive clamp: never allow a wild store outside [0,E)
        if (pos >= 0 && pos < E) {
            col[pos] = src;
            val[pos] = dinv[src] * w[e] * dinv[dst];
        }
    }
    __threadfence();
}

// ---------------- W prep: transpose + bf16 hi/lo split ----------------
__global__ void prep_w_kernel(const float* __restrict__ W,
                              unsigned short* __restrict__ wt_hi,
                              unsigned short* __restrict__ wt_lo) {
    int n = blockIdx.x;    // 0..255 col of W
    int k = threadIdx.x;   // 0..255 row of W
    float v = W[(size_t)k * 256 + n];
    short2 s = split1(v);
    wt_hi[(size_t)n * 256 + k] = (unsigned short)s.x;
    wt_lo[(size_t)n * 256 + k] = (unsigned short)s.y;
    __threadfence();
}

// ---------------- split-bf16 MFMA GEMM ----------------
// C[N][256] (fp32) = A[N][256] @ B[256][256] in ~fp32 precision via 3x bf16 MFMA.
// Block: 256 thr = 4 waves; tile 128 rows x 64 cols; BK=64, single-buffered LDS.
// AFP32: A is fp32, split on the fly. else: A pre-split hi/lo bf16 arrays.
template<bool AFP32>
__global__ __launch_bounds__(256) void gemm_split_kernel(
    const float* __restrict__ Af,
    const unsigned short* __restrict__ Ahg,
    const unsigned short* __restrict__ Alg,
    const unsigned short* __restrict__ Bth,   // Wt_hi [n][k]
    const unsigned short* __restrict__ Btl,   // Wt_lo [n][k]
    float* __restrict__ C, int Nrows)
{
    __shared__ __align__(16) short Ah[128 * 64];
    __shared__ __align__(16) short Al[128 * 64];
    __shared__ __align__(16) short Bh[64 * 64];
    __shared__ __align__(16) short Bl[64 * 64];

    const int t    = threadIdx.x;
    const int lane = t & 63;
    const int w    = t >> 6;
    const int r0   = blockIdx.x * 128;
    const int cb0  = blockIdx.y * 64;
    const int fr   = lane & 15;          // frag row (A: m-row / B: n-col)
    const int fk   = (lane >> 4) * 8;    // frag k offset
    const int wm   = w * 32;             // wave's m-band

    f32x4 acc[2][4] = {};

    for (int k0 = 0; k0 < 256; k0 += 64) {
        __syncthreads();
        // ---- stage B tile [64 n][64 k] (hi+lo) ----
#pragma unroll
        for (int c = 0; c < 2; ++c) {
            int i = c * 256 + t;
            int row = i >> 3, seg = i & 7;
            size_t g = (size_t)(cb0 + row) * 256 + k0 + seg * 8;
            *(s16x8*)&Bh[row * 64 + seg * 8] = *(const s16x8*)(Bth + g);
            *(s16x8*)&Bl[row * 64 + seg * 8] = *(const s16x8*)(Btl + g);
        }
        // ---- stage A tile [128 m][64 k] (hi+lo) ----
        if constexpr (AFP32) {
#pragma unroll
            for (int c = 0; c < 8; ++c) {
                int i = c * 256 + t;
                int row = i >> 4, seg = i & 15;
                int gr = r0 + row; if (gr > Nrows - 1) gr = Nrows - 1;
                float4 v = *(const float4*)(Af + (size_t)gr * 256 + k0 + seg * 4);
                short2 sx = split1(v.x);
                short2 sy = split1(v.y);
                short2 sz = split1(v.z);
                short2 sw = split1(v.w);
                s16x4 hv, lv;
                hv.x = sx.x; hv.y = sy.x; hv.z = sz.x; hv.w = sw.x;
                lv.x = sx.y; lv.y = sy.y; lv.z = sz.y; lv.w = sw.y;
                *(s16x4*)&Ah[row * 64 + seg * 4] = hv;
                *(s16x4*)&Al[row * 64 + seg * 4] = lv;
            }
        } else {
#pragma unroll
            for (int c = 0; c < 4; ++c) {
                int i = c * 256 + t;
                int row = i >> 3, seg = i & 7;
                int gr = r0 + row; if (gr > Nrows - 1) gr = Nrows - 1;
                size_t g = (size_t)gr * 256 + k0 + seg * 8;
                *(s16x8*)&Ah[row * 64 + seg * 8] = *(const s16x8*)(Ahg + g);
                *(s16x8*)&Al[row * 64 + seg * 8] = *(const s16x8*)(Alg + g);
            }
        }
        __syncthreads();
        // ---- compute: 2 k-steps of 32, 2m x 4n frags, 3 MFMA each ----
#pragma unroll
        for (int ks = 0; ks < 2; ++ks) {
            int ko = ks * 32 + fk;
            bf16x8 ah[2], al[2], bh[4], bl[4];
#pragma unroll
            for (int mi = 0; mi < 2; ++mi) {
                ah[mi] = *(const bf16x8*)&Ah[(wm + mi * 16 + fr) * 64 + ko];
                al[mi] = *(const bf16x8*)&Al[(wm + mi * 16 + fr) * 64 + ko];
            }
#pragma unroll
            for (int n = 0; n < 4; ++n) {
                bh[n] = *(const bf16x8*)&Bh[(n * 16 + fr) * 64 + ko];
                bl[n] = *(const bf16x8*)&Bl[(n * 16 + fr) * 64 + ko];
            }
#pragma unroll
            for (int mi = 0; mi < 2; ++mi) {
#pragma unroll
                for (int n = 0; n < 4; ++n) {
                    acc[mi][n] = __builtin_amdgcn_mfma_f32_16x16x32_bf16(ah[mi], bh[n], acc[mi][n], 0, 0, 0);
                    acc[mi][n] = __builtin_amdgcn_mfma_f32_16x16x32_bf16(ah[mi], bl[n], acc[mi][n], 0, 0, 0);
                    acc[mi][n] = __builtin_amdgcn_mfma_f32_16x16x32_bf16(al[mi], bh[n], acc[mi][n], 0, 0, 0);
                }
            }
        }
    }
    // ---- epilogue: C/D layout col=lane&15, row=(lane>>4)*4+reg; store fp32 ----
    const int rb = (lane >> 4) * 4;
#pragma unroll
    for (int mi = 0; mi < 2; ++mi) {
#pragma unroll
        for (int n = 0; n < 4; ++n) {
            int col = cb0 + n * 16 + fr;
#pragma unroll
            for (int r = 0; r < 4; ++r) {
                int row = r0 + wm + mi * 16 + rb + r;
                if (row < Nrows) C[(size_t)row * 256 + col] = acc[mi][n][r];
            }
        }
    }
    __threadfence();   // make C visible device-wide before next kernel
}

// ---------------- CSR aggregation + self loop + bias + relu ----------------
// R4-exact structure (VGPR=40, 226us measured): one WAVE per dst node; lane l
// owns channels [4l,4l+4); unroll-by-8 edge loop with fp32 float4 gathers;
// runtime pointer-branch epilogue. NO fence (R4 passed post-timing without).
__global__ __launch_bounds__(256) void agg_kernel(const float* __restrict__ h,
                                                  const int* __restrict__ rp,
                                                  const int* __restrict__ col,
                                                  const float* __restrict__ val,
                                                  const float* __restrict__ dinv,
                                                  const float* __restrict__ bias,
                                                  float* __restrict__ out,
                                                  unsigned short* __restrict__ out_hi,
                                                  unsigned short* __restrict__ out_lo,
                                                  int N) {
    int d    = blockIdx.x * 4 + (threadIdx.x >> 6);
    int lane = threadIdx.x & 63;
    if (d >= N) return;
    const float4* __restrict__ h4 = (const float4*)h;   // row stride = 64 float4

    float di = dinv[d];
    float4 hv = h4[(size_t)d * 64 + lane];
    float self = di * di;                                // self loop, weight 1
    float4 acc;
    acc.x = self * hv.x; acc.y = self * hv.y;
    acc.z = self * hv.z; acc.w = self * hv.w;

    int s = rp[d], e = rp[d + 1];
    int j = s;
    for (; j + 8 <= e; j += 8) {
        int   c0 = col[j],     c1 = col[j + 1], c2 = col[j + 2], c3 = col[j + 3];
        int   c4 = col[j + 4], c5 = col[j + 5], c6 = col[j + 6], c7 = col[j + 7];
        float v0 = val[j],     v1 = val[j + 1], v2 = val[j + 2], v3 = val[j + 3];
        float v4 = val[j + 4], v5 = val[j + 5], v6 = val[j + 6], v7 = val[j + 7];
        float4 a0 = h4[(size_t)c0 * 64 + lane];
        float4 a1 = h4[(size_t)c1 * 64 + lane];
        float4 a2 = h4[(size_t)c2 * 64 + lane];
        float4 a3 = h4[(size_t)c3 * 64 + lane];
        float4 a4 = h4[(size_t)c4 * 64 + lane];
        float4 a5 = h4[(size_t)c5 * 64 + lane];
        float4 a6 = h4[(size_t)c6 * 64 + lane];
        float4 a7 = h4[(size_t)c7 * 64 + lane];
        acc.x = fmaf(v0, a0.x, acc.x); acc.y = fmaf(v0, a0.y, acc.y);
        acc.z = fmaf(v0, a0.z, acc.z); acc.w = fmaf(v0, a0.w, acc.w);
        acc.x = fmaf(v1, a1.x, acc.x); acc.y = fmaf(v1, a1.y, acc.y);
        acc.z = fmaf(v1, a1.z, acc.z); acc.w = fmaf(v1, a1.w, acc.w);
        acc.x = fmaf(v2, a2.x, acc.x); acc.y = fmaf(v2, a2.y, acc.y);
        acc.z = fmaf(v2, a2.z, acc.z); acc.w = fmaf(v2, a2.w, acc.w);
        acc.x = fmaf(v3, a3.x, acc.x); acc.y = fmaf(v3, a3.y, acc.y);
        acc.z = fmaf(v3, a3.z, acc.z); acc.w = fmaf(v3, a3.w, acc.w);
        acc.x = fmaf(v4, a4.x, acc.x); acc.y = fmaf(v4, a4.y, acc.y);
        acc.z = fmaf(v4, a4.z, acc.z); acc.w = fmaf(v4, a4.w, acc.w);
        acc.x = fmaf(v5, a5.x, acc.x); acc.y = fmaf(v5, a5.y, acc.y);
        acc.z = fmaf(v5, a5.z, acc.z); acc.w = fmaf(v5, a5.w, acc.w);
        acc.x = fmaf(v6, a6.x, acc.x); acc.y = fmaf(v6, a6.y, acc.y);
        acc.z = fmaf(v6, a6.z, acc.z); acc.w = fmaf(v6, a6.w, acc.w);
        acc.x = fmaf(v7, a7.x, acc.x); acc.y = fmaf(v7, a7.y, acc.y);
        acc.z = fmaf(v7, a7.z, acc.z); acc.w = fmaf(v7, a7.w, acc.w);
    }
    for (; j < e; ++j) {
        int   c = col[j];
        float v = val[j];
        float4 a = h4[(size_t)c * 64 + lane];
        acc.x = fmaf(v, a.x, acc.x); acc.y = fmaf(v, a.y, acc.y);
        acc.z = fmaf(v, a.z, acc.z); acc.w = fmaf(v, a.w, acc.w);
    }

    float4 b = *(const float4*)(bias + lane * 4);
    acc.x = fmaxf(acc.x + b.x, 0.0f);
    acc.y = fmaxf(acc.y + b.y, 0.0f);
    acc.z = fmaxf(acc.z + b.z, 0.0f);
    acc.w = fmaxf(acc.w + b.w, 0.0f);

    if (out_hi != nullptr) {
        short2 sx = split1(acc.x);
        short2 sy = split1(acc.y);
        short2 sz = split1(acc.z);
        short2 sw = split1(acc.w);
        s16x4 hvv, lvv;
        hvv.x = sx.x; hvv.y = sy.x; hvv.z = sz.x; hvv.w = sw.x;
        lvv.x = sx.y; lvv.y = sy.y; lvv.z = sz.y; lvv.w = sw.y;
        *(s16x4*)(out_hi + (size_t)d * 256 + lane * 4) = hvv;
        *(s16x4*)(out_lo + (size_t)d * 256 + lane * 4) = lvv;
    } else {
        ((float4*)out)[(size_t)d * 64 + lane] = acc;
    }
}

// ---------------- regression head: out = h @ Wf + bf, one wave per node ----------------
__global__ __launch_bounds__(256) void head_kernel(const float* __restrict__ h,
                                                   const float* __restrict__ Wf,
                                                   const float* __restrict__ bf,
                                                   float* __restrict__ out, int N) {
    int gid  = blockIdx.x * blockDim.x + threadIdx.x;
    int wid  = gid >> 6;
    int lane = gid & 63;
    if (wid >= N) return;
    float4 hv = *(const float4*)(h + (size_t)wid * 256 + lane * 4);
    float4 wv = *(const float4*)(Wf + lane * 4);
    float s = hv.x * wv.x + hv.y * wv.y + hv.z * wv.z + hv.w * wv.w;
    for (int off = 32; off; off >>= 1) s += __shfl_down(s, off);
    if (lane == 0) out[wid] = s + bf[0];
}

// ---------------- host launch ----------------
extern "C" void kernel_launch(void* const* d_in, const int* in_sizes, int n_in,
                              void* d_out, int out_size, void* d_ws, size_t ws_size,
                              hipStream_t stream) {
    const float* x  = (const float*)d_in[0];
    const int*   ei = (const int*)d_in[1];
    const float* w  = (const float*)d_in[2];
    const float* W1 = (const float*)d_in[3];
    const float* b1 = (const float*)d_in[4];
    const float* W2 = (const float*)d_in[5];
    const float* b2 = (const float*)d_in[6];
    const float* Wf = (const float*)d_in[7];
    const float* bf = (const float*)d_in[8];
    float* out = (float*)d_out;

    const int N = in_sizes[0] / IN_C;
    const int E = in_sizes[2];

    // workspace layout (256B aligned) — R4-exact
    auto align256 = [](size_t v) { return (v + 255) & ~(size_t)255; };
    char* p = (char*)d_ws;
    float* deg    = (float*)p; p += align256((size_t)N * 4);
    float* dinv   = (float*)p; p += align256((size_t)N * 4);
    int*   cnt    = (int*)p;   p += align256((size_t)N * 4);
    int*   rp     = (int*)p;   p += align256(((size_t)N + 1) * 4);
    int*   cursor = (int*)p;   p += align256((size_t)N * 4);
    int*   bsum   = (int*)p;   p += align256(SCAN_B * 4);
    int*   boff   = (int*)p;   p += align256(SCAN_B * 4);
    int*   col    = (int*)p;   p += align256((size_t)E * 4);
    float* val    = (float*)p; p += align256((size_t)E * 4);
    unsigned short* w1t_hi = (unsigned short*)p; p += align256((size_t)256 * 256 * 2);
    unsigned short* w1t_lo = (unsigned short*)p; p += align256((size_t)256 * 256 * 2);
    unsigned short* w2t_hi = (unsigned short*)p; p += align256((size_t)256 * 256 * 2);
    unsigned short* w2t_lo = (unsigned short*)p; p += align256((size_t)256 * 256 * 2);
    float* hbuf   = (float*)p; p += align256((size_t)N * 256 * 4);
    // a_hi/a_lo (layer-1 activations, bf16 split) alias abuf2 (fp32, layer-2
    // output): a_hi/lo are dead once GEMM2 finishes; agg2 runs after GEMM2.
    char* abase = p;
    unsigned short* a_hi = (unsigned short*)abase;
    unsigned short* a_lo = (unsigned short*)(abase + align256((size_t)N * 256 * 2));
    float* abuf2 = (float*)abase;                 // N*256*4 bytes, aliases a_hi+a_lo
    p = abase + align256((size_t)N * 256 * 2) + align256((size_t)N * 256 * 2);
    (void)ws_size; (void)n_in; (void)out_size;

    const int nb_nodes = (N + 255) / 256;
    const int nb_edges = (E + 255) / 256;
    const int nb_scan  = (N + SCAN_B - 1) / SCAN_B;

    // graph normalization + CSR build
    init_kernel<<<nb_nodes, 256, 0, stream>>>(deg, cnt, N);
    deg_count_kernel<<<nb_edges, 256, 0, stream>>>(ei, w, deg, cnt, E);
    dinv_kernel<<<nb_nodes, 256, 0, stream>>>(deg, dinv, N);
    scan1_kernel<<<nb_scan, SCAN_B, 0, stream>>>(cnt, rp, bsum, N);
    scan2_kernel<<<1, SCAN_B, 0, stream>>>(bsum, boff, nb_scan);
    scan3_kernel<<<nb_nodes, 256, 0, stream>>>(rp, cursor, boff, N, E);
    fill_kernel<<<nb_edges, 256, 0, stream>>>(ei, w, dinv, cursor, col, val, E);

    // weight prep (transpose + hi/lo split)
    prep_w_kernel<<<256, 256, 0, stream>>>(W1, w1t_hi, w1t_lo);
    prep_w_kernel<<<256, 256, 0, stream>>>(W2, w2t_hi, w2t_lo);

    dim3 ggrid((N + 127) / 128, 4);
    const int nb_agg = (N + 3) / 4;

    // layer 1: GEMM (fp32 A, on-the-fly split) -> fp32 h -> agg (writes bf16 hi/lo)
    gemm_split_kernel<true><<<ggrid, 256, 0, stream>>>(x, nullptr, nullptr,
                                                       w1t_hi, w1t_lo, hbuf, N);
    agg_kernel<<<nb_agg, 256, 0, stream>>>(hbuf, rp, col, val, dinv, b1,
                                           nullptr, a_hi, a_lo, N);
    // layer 2: GEMM (pre-split bf16 A) -> fp32 h -> agg (writes fp32)
    gemm_split_kernel<false><<<ggrid, 256, 0, stream>>>(nullptr, a_hi, a_lo,
                                                        w2t_hi, w2t_lo, hbuf, N);
    agg_kernel<<<nb_agg, 256, 0, stream>>>(hbuf, rp, col, val, dinv, b2,
                                           abuf2, nullptr, nullptr, N);
    // head
    head_kernel<<<(N * 64 + 255) / 256, 256, 0, stream>>>(abuf2, Wf, bf, out, N);
}

// Round 9
// 836.655 us; speedup vs baseline: 4.2466x; 2.8340x over previous
//
#include <hip/hip_runtime.h>
#include <hip/hip_bf16.h>
#include <cstdint>

#define IN_C 256

typedef __attribute__((ext_vector_type(8))) short bf16x8;
typedef __attribute__((ext_vector_type(8))) short s16x8;
typedef __attribute__((ext_vector_type(4))) short s16x4;
typedef __attribute__((ext_vector_type(4))) float f32x4;

// ---- bf16 split helpers (RNE) ----
__device__ inline unsigned short f2bf(float f) {
    union { float f; unsigned int u; } v; v.f = f;
    unsigned int r = (v.u + 0x7fffu + ((v.u >> 16) & 1u)) >> 16;
    return (unsigned short)r;
}
__device__ inline float bf2f(unsigned short b) {
    union { unsigned int u; float f; } v; v.u = ((unsigned int)b) << 16;
    return v.f;
}
// returns .x = hi bf16 bits, .y = lo bf16 bits
__device__ inline short2 split1(float f) {
    unsigned short hb = f2bf(f);
    unsigned short lb = f2bf(f - bf2f(hb));
    return make_short2((short)hb, (short)lb);
}

// ---------------- init: deg=1 (self loop weight), cnt=0 ----------------
__global__ void init_kernel(float* __restrict__ deg, int* __restrict__ cnt, int N) {
    int i = blockIdx.x * blockDim.x + threadIdx.x;
    if (i < N) { deg[i] = 1.0f; cnt[i] = 0; }
}

// ---------------- per-edge: degree accumulate + dst histogram ----------------
__global__ void deg_count_kernel(const int* __restrict__ ei, const float* __restrict__ w,
                                 float* __restrict__ deg, int* __restrict__ cnt, int E) {
    int e = blockIdx.x * blockDim.x + threadIdx.x;
    if (e >= E) return;
    int dst = ei[E + e];
    atomicAdd(&deg[dst], w[e]);
    atomicAdd(&cnt[dst], 1);
}

__global__ void dinv_kernel(const float* __restrict__ deg, float* __restrict__ dinv, int N) {
    int i = blockIdx.x * blockDim.x + threadIdx.x;
    if (i < N) dinv[i] = rsqrtf(deg[i]);   // deg >= 1 always (self loop)
}

// ---------------- exclusive scan of cnt -> row_ptr (3-kernel) ----------------
#define SCAN_B 256
__global__ void scan1_kernel(const int* __restrict__ cnt, int* __restrict__ rp,
                             int* __restrict__ bsum, int N) {
    __shared__ int s[SCAN_B];
    int tid = threadIdx.x;
    int i = blockIdx.x * SCAN_B + tid;
    int v = (i < N) ? cnt[i] : 0;
    s[tid] = v;
    __syncthreads();
    for (int off = 1; off < SCAN_B; off <<= 1) {
        int t = (tid >= off) ? s[tid - off] : 0;
        __syncthreads();
        s[tid] += t;
        __syncthreads();
    }
    if (i < N) rp[i] = s[tid] - v;            // exclusive within block
    if (tid == SCAN_B - 1) bsum[blockIdx.x] = s[tid];
}

__global__ void scan2_kernel(int* __restrict__ bsum, int* __restrict__ boff, int nb) {
    __shared__ int s[SCAN_B];
    int tid = threadIdx.x;
    int v = (tid < nb) ? bsum[tid] : 0;
    s[tid] = v;
    __syncthreads();
    for (int off = 1; off < SCAN_B; off <<= 1) {
        int t = (tid >= off) ? s[tid - off] : 0;
        __syncthreads();
        s[tid] += t;
        __syncthreads();
    }
    if (tid < nb) boff[tid] = s[tid] - v;     // exclusive across blocks
}

__global__ void scan3_kernel(int* __restrict__ rp, int* __restrict__ cursor,
                             const int* __restrict__ boff, int N, int E) {
    int i = blockIdx.x * blockDim.x + threadIdx.x;
    if (i < N) {
        int r = rp[i] + boff[i >> 8];
        rp[i] = r;
        cursor[i] = r;
    }
    if (i == 0) rp[N] = E;
}

// ---------------- CSR fill with per-edge norm ----------------
__global__ void fill_kernel(const int* __restrict__ ei, const float* __restrict__ w,
                            const float* __restrict__ dinv, int* __restrict__ cursor,
                            int* __restrict__ col, float* __restrict__ val, int E) {
    int e = blockIdx.x * blockDim.x + threadIdx.x;
    if (e >= E) return;
    int src = ei[e];
    int dst = ei[E + e];
    int pos = atomicAdd(&cursor[dst], 1);
    // defensive clamp: never allow a wild store outside [0,E)
    if (pos >= 0 && pos < E) {
        col[pos] = src;
        val[pos] = dinv[src] * w[e] * dinv[dst];
    }
}

// ---------------- W prep: transpose + bf16 hi/lo split ----------------
__global__ void prep_w_kernel(const float* __restrict__ W,
                              unsigned short* __restrict__ wt_hi,
                              unsigned short* __restrict__ wt_lo) {
    int n = blockIdx.x;    // 0..255 col of W
    int k = threadIdx.x;   // 0..255 row of W
    float v = W[(size_t)k * 256 + n];
    short2 s = split1(v);
    wt_hi[(size_t)n * 256 + k] = (unsigned short)s.x;
    wt_lo[(size_t)n * 256 + k] = (unsigned short)s.y;
}

// ---------------- split-bf16 MFMA GEMM ----------------
// C[N][256] (fp32) = A[N][256] @ B[256][256] in ~fp32 precision via 3x bf16 MFMA.
// Block: 256 thr = 4 waves; tile 128 rows x 64 cols; BK=64, single-buffered LDS.
// AFP32: A is fp32, split on the fly. else: A pre-split hi/lo bf16 arrays.
template<bool AFP32>
__global__ __launch_bounds__(256) void gemm_split_kernel(
    const float* __restrict__ Af,
    const unsigned short* __restrict__ Ahg,
    const unsigned short* __restrict__ Alg,
    const unsigned short* __restrict__ Bth,   // Wt_hi [n][k]
    const unsigned short* __restrict__ Btl,   // Wt_lo [n][k]
    float* __restrict__ C, int Nrows)
{
    __shared__ __align__(16) short Ah[128 * 64];
    __shared__ __align__(16) short Al[128 * 64];
    __shared__ __align__(16) short Bh[64 * 64];
    __shared__ __align__(16) short Bl[64 * 64];

    const int t    = threadIdx.x;
    const int lane = t & 63;
    const int w    = t >> 6;
    const int r0   = blockIdx.x * 128;
    const int cb0  = blockIdx.y * 64;
    const int fr   = lane & 15;          // frag row (A: m-row / B: n-col)
    const int fk   = (lane >> 4) * 8;    // frag k offset
    const int wm   = w * 32;             // wave's m-band

    f32x4 acc[2][4] = {};

    for (int k0 = 0; k0 < 256; k0 += 64) {
        __syncthreads();
        // ---- stage B tile [64 n][64 k] (hi+lo) ----
#pragma unroll
        for (int c = 0; c < 2; ++c) {
            int i = c * 256 + t;
            int row = i >> 3, seg = i & 7;
            size_t g = (size_t)(cb0 + row) * 256 + k0 + seg * 8;
            *(s16x8*)&Bh[row * 64 + seg * 8] = *(const s16x8*)(Bth + g);
            *(s16x8*)&Bl[row * 64 + seg * 8] = *(const s16x8*)(Btl + g);
        }
        // ---- stage A tile [128 m][64 k] (hi+lo) ----
        if constexpr (AFP32) {
#pragma unroll
            for (int c = 0; c < 8; ++c) {
                int i = c * 256 + t;
                int row = i >> 4, seg = i & 15;
                int gr = r0 + row; if (gr > Nrows - 1) gr = Nrows - 1;
                float4 v = *(const float4*)(Af + (size_t)gr * 256 + k0 + seg * 4);
                short2 sx = split1(v.x);
                short2 sy = split1(v.y);
                short2 sz = split1(v.z);
                short2 sw = split1(v.w);
                s16x4 hv, lv;
                hv.x = sx.x; hv.y = sy.x; hv.z = sz.x; hv.w = sw.x;
                lv.x = sx.y; lv.y = sy.y; lv.z = sz.y; lv.w = sw.y;
                *(s16x4*)&Ah[row * 64 + seg * 4] = hv;
                *(s16x4*)&Al[row * 64 + seg * 4] = lv;
            }
        } else {
#pragma unroll
            for (int c = 0; c < 4; ++c) {
                int i = c * 256 + t;
                int row = i >> 3, seg = i & 7;
                int gr = r0 + row; if (gr > Nrows - 1) gr = Nrows - 1;
                size_t g = (size_t)gr * 256 + k0 + seg * 8;
                *(s16x8*)&Ah[row * 64 + seg * 8] = *(const s16x8*)(Ahg + g);
                *(s16x8*)&Al[row * 64 + seg * 8] = *(const s16x8*)(Alg + g);
            }
        }
        __syncthreads();
        // ---- compute: 2 k-steps of 32, 2m x 4n frags, 3 MFMA each ----
#pragma unroll
        for (int ks = 0; ks < 2; ++ks) {
            int ko = ks * 32 + fk;
            bf16x8 ah[2], al[2], bh[4], bl[4];
#pragma unroll
            for (int mi = 0; mi < 2; ++mi) {
                ah[mi] = *(const bf16x8*)&Ah[(wm + mi * 16 + fr) * 64 + ko];
                al[mi] = *(const bf16x8*)&Al[(wm + mi * 16 + fr) * 64 + ko];
            }
#pragma unroll
            for (int n = 0; n < 4; ++n) {
                bh[n] = *(const bf16x8*)&Bh[(n * 16 + fr) * 64 + ko];
                bl[n] = *(const bf16x8*)&Bl[(n * 16 + fr) * 64 + ko];
            }
#pragma unroll
            for (int mi = 0; mi < 2; ++mi) {
#pragma unroll
                for (int n = 0; n < 4; ++n) {
                    acc[mi][n] = __builtin_amdgcn_mfma_f32_16x16x32_bf16(ah[mi], bh[n], acc[mi][n], 0, 0, 0);
                    acc[mi][n] = __builtin_amdgcn_mfma_f32_16x16x32_bf16(ah[mi], bl[n], acc[mi][n], 0, 0, 0);
                    acc[mi][n] = __builtin_amdgcn_mfma_f32_16x16x32_bf16(al[mi], bh[n], acc[mi][n], 0, 0, 0);
                }
            }
        }
    }
    // ---- epilogue: C/D layout col=lane&15, row=(lane>>4)*4+reg; store fp32 ----
    const int rb = (lane >> 4) * 4;
#pragma unroll
    for (int mi = 0; mi < 2; ++mi) {
#pragma unroll
        for (int n = 0; n < 4; ++n) {
            int col = cb0 + n * 16 + fr;
#pragma unroll
            for (int r = 0; r < 4; ++r) {
                int row = r0 + wm + mi * 16 + rb + r;
                if (row < Nrows) C[(size_t)row * 256 + col] = acc[mi][n][r];
            }
        }
    }
}

// ---------------- CSR aggregation + self loop + bias + relu ----------------
// R4-exact structure (VGPR=40, 226us measured): one WAVE per dst node; lane l
// owns channels [4l,4l+4); unroll-by-8 edge loop with fp32 float4 gathers
// (8 independent 1KB row-gathers in flight); runtime pointer-branch epilogue.
// NOTE: bf16 h-gather (ushort4) was tried in R6/R7 and is 6.7x SLOWER despite
// half the bytes — do not reintroduce.
__global__ __launch_bounds__(256) void agg_kernel(const float* __restrict__ h,
                                                  const int* __restrict__ rp,
                                                  const int* __restrict__ col,
                                                  const float* __restrict__ val,
                                                  const float* __restrict__ dinv,
                                                  const float* __restrict__ bias,
                                                  float* __restrict__ out,
                                                  unsigned short* __restrict__ out_hi,
                                                  unsigned short* __restrict__ out_lo,
                                                  int N) {
    int d    = blockIdx.x * 4 + (threadIdx.x >> 6);
    int lane = threadIdx.x & 63;
    if (d >= N) return;
    const float4* __restrict__ h4 = (const float4*)h;   // row stride = 64 float4

    float di = dinv[d];
    float4 hv = h4[(size_t)d * 64 + lane];
    float self = di * di;                                // self loop, weight 1
    float4 acc;
    acc.x = self * hv.x; acc.y = self * hv.y;
    acc.z = self * hv.z; acc.w = self * hv.w;

    int s = rp[d], e = rp[d + 1];
    int j = s;
    for (; j + 8 <= e; j += 8) {
        int   c0 = col[j],     c1 = col[j + 1], c2 = col[j + 2], c3 = col[j + 3];
        int   c4 = col[j + 4], c5 = col[j + 5], c6 = col[j + 6], c7 = col[j + 7];
        float v0 = val[j],     v1 = val[j + 1], v2 = val[j + 2], v3 = val[j + 3];
        float v4 = val[j + 4], v5 = val[j + 5], v6 = val[j + 6], v7 = val[j + 7];
        float4 a0 = h4[(size_t)c0 * 64 + lane];
        float4 a1 = h4[(size_t)c1 * 64 + lane];
        float4 a2 = h4[(size_t)c2 * 64 + lane];
        float4 a3 = h4[(size_t)c3 * 64 + lane];
        float4 a4 = h4[(size_t)c4 * 64 + lane];
        float4 a5 = h4[(size_t)c5 * 64 + lane];
        float4 a6 = h4[(size_t)c6 * 64 + lane];
        float4 a7 = h4[(size_t)c7 * 64 + lane];
        acc.x = fmaf(v0, a0.x, acc.x); acc.y = fmaf(v0, a0.y, acc.y);
        acc.z = fmaf(v0, a0.z, acc.z); acc.w = fmaf(v0, a0.w, acc.w);
        acc.x = fmaf(v1, a1.x, acc.x); acc.y = fmaf(v1, a1.y, acc.y);
        acc.z = fmaf(v1, a1.z, acc.z); acc.w = fmaf(v1, a1.w, acc.w);
        acc.x = fmaf(v2, a2.x, acc.x); acc.y = fmaf(v2, a2.y, acc.y);
        acc.z = fmaf(v2, a2.z, acc.z); acc.w = fmaf(v2, a2.w, acc.w);
        acc.x = fmaf(v3, a3.x, acc.x); acc.y = fmaf(v3, a3.y, acc.y);
        acc.z = fmaf(v3, a3.z, acc.z); acc.w = fmaf(v3, a3.w, acc.w);
        acc.x = fmaf(v4, a4.x, acc.x); acc.y = fmaf(v4, a4.y, acc.y);
        acc.z = fmaf(v4, a4.z, acc.z); acc.w = fmaf(v4, a4.w, acc.w);
        acc.x = fmaf(v5, a5.x, acc.x); acc.y = fmaf(v5, a5.y, acc.y);
        acc.z = fmaf(v5, a5.z, acc.z); acc.w = fmaf(v5, a5.w, acc.w);
        acc.x = fmaf(v6, a6.x, acc.x); acc.y = fmaf(v6, a6.y, acc.y);
        acc.z = fmaf(v6, a6.z, acc.z); acc.w = fmaf(v6, a6.w, acc.w);
        acc.x = fmaf(v7, a7.x, acc.x); acc.y = fmaf(v7, a7.y, acc.y);
        acc.z = fmaf(v7, a7.z, acc.z); acc.w = fmaf(v7, a7.w, acc.w);
    }
    for (; j < e; ++j) {
        int   c = col[j];
        float v = val[j];
        float4 a = h4[(size_t)c * 64 + lane];
        acc.x = fmaf(v, a.x, acc.x); acc.y = fmaf(v, a.y, acc.y);
        acc.z = fmaf(v, a.z, acc.z); acc.w = fmaf(v, a.w, acc.w);
    }

    float4 b = *(const float4*)(bias + lane * 4);
    acc.x = fmaxf(acc.x + b.x, 0.0f);
    acc.y = fmaxf(acc.y + b.y, 0.0f);
    acc.z = fmaxf(acc.z + b.z, 0.0f);
    acc.w = fmaxf(acc.w + b.w, 0.0f);

    if (out_hi != nullptr) {
        short2 sx = split1(acc.x);
        short2 sy = split1(acc.y);
        short2 sz = split1(acc.z);
        short2 sw = split1(acc.w);
        s16x4 hvv, lvv;
        hvv.x = sx.x; hvv.y = sy.x; hvv.z = sz.x; hvv.w = sw.x;
        lvv.x = sx.y; lvv.y = sy.y; lvv.z = sz.y; lvv.w = sw.y;
        *(s16x4*)(out_hi + (size_t)d * 256 + lane * 4) = hvv;
        *(s16x4*)(out_lo + (size_t)d * 256 + lane * 4) = lvv;
    } else {
        ((float4*)out)[(size_t)d * 64 + lane] = acc;
    }
}

// ---------------- regression head: out = h @ Wf + bf, one wave per node ----------------
__global__ __launch_bounds__(256) void head_kernel(const float* __restrict__ h,
                                                   const float* __restrict__ Wf,
                                                   const float* __restrict__ bf,
                                                   float* __restrict__ out, int N) {
    int gid  = blockIdx.x * blockDim.x + threadIdx.x;
    int wid  = gid >> 6;
    int lane = gid & 63;
    if (wid >= N) return;
    float4 hv = *(const float4*)(h + (size_t)wid * 256 + lane * 4);
    float4 wv = *(const float4*)(Wf + lane * 4);
    float s = hv.x * wv.x + hv.y * wv.y + hv.z * wv.z + hv.w * wv.w;
    for (int off = 32; off; off >>= 1) s += __shfl_down(s, off);
    if (lane == 0) out[wid] = s + bf[0];
}

// ---------------- host launch ----------------
extern "C" void kernel_launch(void* const* d_in, const int* in_sizes, int n_in,
                              void* d_out, int out_size, void* d_ws, size_t ws_size,
                              hipStream_t stream) {
    const float* x  = (const float*)d_in[0];
    const int*   ei = (const int*)d_in[1];
    const float* w  = (const float*)d_in[2];
    const float* W1 = (const float*)d_in[3];
    const float* b1 = (const float*)d_in[4];
    const float* W2 = (const float*)d_in[5];
    const float* b2 = (const float*)d_in[6];
    const float* Wf = (const float*)d_in[7];
    const float* bf = (const float*)d_in[8];
    float* out = (float*)d_out;

    const int N = in_sizes[0] / IN_C;
    const int E = in_sizes[2];

    // workspace layout (256B aligned) — R4-exact
    auto align256 = [](size_t v) { return (v + 255) & ~(size_t)255; };
    char* p = (char*)d_ws;
    float* deg    = (float*)p; p += align256((size_t)N * 4);
    float* dinv   = (float*)p; p += align256((size_t)N * 4);
    int*   cnt    = (int*)p;   p += align256((size_t)N * 4);
    int*   rp     = (int*)p;   p += align256(((size_t)N + 1) * 4);
    int*   cursor = (int*)p;   p += align256((size_t)N * 4);
    int*   bsum   = (int*)p;   p += align256(SCAN_B * 4);
    int*   boff   = (int*)p;   p += align256(SCAN_B * 4);
    int*   col    = (int*)p;   p += align256((size_t)E * 4);
    float* val    = (float*)p; p += align256((size_t)E * 4);
    unsigned short* w1t_hi = (unsigned short*)p; p += align256((size_t)256 * 256 * 2);
    unsigned short* w1t_lo = (unsigned short*)p; p += align256((size_t)256 * 256 * 2);
    unsigned short* w2t_hi = (unsigned short*)p; p += align256((size_t)256 * 256 * 2);
    unsigned short* w2t_lo = (unsigned short*)p; p += align256((size_t)256 * 256 * 2);
    float* hbuf   = (float*)p; p += align256((size_t)N * 256 * 4);
    // a_hi/a_lo (layer-1 activations, bf16 split) alias abuf2 (fp32, layer-2
    // output): a_hi/lo are dead once GEMM2 finishes; agg2 runs after GEMM2.
    char* abase = p;
    unsigned short* a_hi = (unsigned short*)abase;
    unsigned short* a_lo = (unsigned short*)(abase + align256((size_t)N * 256 * 2));
    float* abuf2 = (float*)abase;                 // N*256*4 bytes, aliases a_hi+a_lo
    p = abase + align256((size_t)N * 256 * 2) + align256((size_t)N * 256 * 2);
    (void)ws_size; (void)n_in; (void)out_size;

    const int nb_nodes = (N + 255) / 256;
    const int nb_edges = (E + 255) / 256;
    const int nb_scan  = (N + SCAN_B - 1) / SCAN_B;

    // graph normalization + CSR build
    init_kernel<<<nb_nodes, 256, 0, stream>>>(deg, cnt, N);
    deg_count_kernel<<<nb_edges, 256, 0, stream>>>(ei, w, deg, cnt, E);
    dinv_kernel<<<nb_nodes, 256, 0, stream>>>(deg, dinv, N);
    scan1_kernel<<<nb_scan, SCAN_B, 0, stream>>>(cnt, rp, bsum, N);
    scan2_kernel<<<1, SCAN_B, 0, stream>>>(bsum, boff, nb_scan);
    scan3_kernel<<<nb_nodes, 256, 0, stream>>>(rp, cursor, boff, N, E);
    fill_kernel<<<nb_edges, 256, 0, stream>>>(ei, w, dinv, cursor, col, val, E);

    // weight prep (transpose + hi/lo split)
    prep_w_kernel<<<256, 256, 0, stream>>>(W1, w1t_hi, w1t_lo);
    prep_w_kernel<<<256, 256, 0, stream>>>(W2, w2t_hi, w2t_lo);

    dim3 ggrid((N + 127) / 128, 4);
    const int nb_agg = (N + 3) / 4;

    // layer 1: GEMM (fp32 A, on-the-fly split) -> fp32 h -> agg (writes bf16 hi/lo)
    gemm_split_kernel<true><<<ggrid, 256, 0, stream>>>(x, nullptr, nullptr,
                                                       w1t_hi, w1t_lo, hbuf, N);
    agg_kernel<<<nb_agg, 256, 0, stream>>>(hbuf, rp, col, val, dinv, b1,
                                           nullptr, a_hi, a_lo, N);
    // layer 2: GEMM (pre-split bf16 A) -> fp32 h -> agg (writes fp32)
    gemm_split_kernel<false><<<ggrid, 256, 0, stream>>>(nullptr, a_hi, a_lo,
                                                        w2t_hi, w2t_lo, hbuf, N);
    agg_kernel<<<nb_agg, 256, 0, stream>>>(hbuf, rp, col, val, dinv, b2,
                                           abuf2, nullptr, nullptr, N);
    // head
    head_kernel<<<(N * 64 + 255) / 256, 256, 0, stream>>>(abuf2, Wf, bf, out, N);
}